// Round 3
// baseline (15901.508 us; speedup 1.0000x reference)
//
#include <hip/hip_runtime.h>
#include <math.h>

#define TT 64
#define BB 2048
#define NBLK 256

using f32x4  = __attribute__((ext_vector_type(4))) float;
using short8 = __attribute__((ext_vector_type(8))) short;

__device__ __forceinline__ unsigned short f2bf(float f) {
    unsigned u = __float_as_uint(f);
    u += 0x7FFF + ((u >> 16) & 1);
    return (unsigned short)(u >> 16);
}
__device__ __forceinline__ float sigmoidf_(float v) { return 1.0f / (1.0f + expf(-v)); }
__device__ __forceinline__ float tanhf_(float v)    { return 1.0f - 2.0f / (expf(2.0f * v) + 1.0f); }

// ---------------- weight f32 -> bf16 convert ----------------
__global__ __launch_bounds__(256)
void cvt_kernel(const float* __restrict__ src, unsigned short* __restrict__ dst, int n) {
    int i = blockIdx.x * 256 + threadIdx.x;
    if (i < n) dst[i] = f2bf(src[i]);
}

// one wave handles one 512-wide row: LN -> bf16
__device__ __forceinline__ void ln_row_wave(const float* __restrict__ xr,
                                            const float* __restrict__ g,
                                            const float* __restrict__ b,
                                            unsigned short* __restrict__ yr, int lane) {
    const int c0 = lane * 8;
    float4 v0 = *(const float4*)(xr + c0);
    float4 v1 = *(const float4*)(xr + c0 + 4);
    float s  = v0.x + v0.y + v0.z + v0.w + v1.x + v1.y + v1.z + v1.w;
    float ss = v0.x*v0.x + v0.y*v0.y + v0.z*v0.z + v0.w*v0.w
             + v1.x*v1.x + v1.y*v1.y + v1.z*v1.z + v1.w*v1.w;
#pragma unroll
    for (int m = 32; m > 0; m >>= 1) { s += __shfl_xor(s, m); ss += __shfl_xor(ss, m); }
    const float mean = s * (1.0f / 512.0f);
    const float var  = ss * (1.0f / 512.0f) - mean * mean;
    const float rs   = rsqrtf(var + 1e-5f);
    float4 g0 = *(const float4*)(g + c0);
    float4 g1 = *(const float4*)(g + c0 + 4);
    float4 b0 = *(const float4*)(b + c0);
    float4 b1 = *(const float4*)(b + c0 + 4);
    short8 o;
    o[0] = (short)f2bf((v0.x - mean) * rs * g0.x + b0.x);
    o[1] = (short)f2bf((v0.y - mean) * rs * g0.y + b0.y);
    o[2] = (short)f2bf((v0.z - mean) * rs * g0.z + b0.z);
    o[3] = (short)f2bf((v0.w - mean) * rs * g0.w + b0.w);
    o[4] = (short)f2bf((v1.x - mean) * rs * g1.x + b1.x);
    o[5] = (short)f2bf((v1.y - mean) * rs * g1.y + b1.y);
    o[6] = (short)f2bf((v1.z - mean) * rs * g1.z + b1.z);
    o[7] = (short)f2bf((v1.w - mean) * rs * g1.w + b1.w);
    *(short8*)(yr + c0) = o;
}

__global__ __launch_bounds__(256)
void ln_x_kernel(const float* __restrict__ x, const float* __restrict__ g,
                 const float* __restrict__ b, unsigned short* __restrict__ y)
{
    const int wave = threadIdx.x >> 6;
    const int lane = threadIdx.x & 63;
    const int row  = blockIdx.x * 4 + wave;
    ln_row_wave(x + (size_t)row * 512, g, b, y + (size_t)row * 512, lane);
}

// device-scope grid barrier: monotonically increasing counter (reset per launch)
__device__ __forceinline__ void gsync(unsigned* bar, unsigned target) {
    __syncthreads();
    if (threadIdx.x == 0) {
        __threadfence();
        __hip_atomic_fetch_add(bar, 1u, __ATOMIC_ACQ_REL, __HIP_MEMORY_SCOPE_AGENT);
        while (__hip_atomic_load(bar, __ATOMIC_ACQUIRE, __HIP_MEMORY_SCOPE_AGENT) < target)
            __builtin_amdgcn_s_sleep(2);
    }
    __syncthreads();
}

// ---------------- persistent recurrent kernel: entire T loop ----------------
// 256 blocks x 512 threads (8 waves). Co-resident: 1 block/CU.
// Phase A (all 256 blocks): RZ = sigmoid([xn_t | hn] @ Wrz^T + b)  [2048 x 1024]
//   block tile 64x128: m-tile = b>>3, n-tile = b&7. r-side writes bf16(r*hn), z-side writes z_f32.
// Phase B (blocks 0..127): C = [xn_t | r*hn] @ Wc^T + bc -> h_new -> LN_cell -> states[t]
//   -> LN_h * exp(-dt) -> hn (f32 + bf16). Block owns 16 full rows (LN local).
// Phase B (blocks 128..255): xn[t+1] = LN(seq[t+1]) (16 rows each).
__global__ __launch_bounds__(512)
void recurrent_kernel(const float* __restrict__ seq, const float* __restrict__ ts,
                      const unsigned short* __restrict__ Wrz, const unsigned short* __restrict__ Wc,
                      const float* __restrict__ br, const float* __restrict__ bz,
                      const float* __restrict__ bc,
                      const float* __restrict__ gx, const float* __restrict__ bx,
                      const float* __restrict__ gh, const float* __restrict__ bh,
                      const float* __restrict__ gc, const float* __restrict__ bcl,
                      unsigned short* __restrict__ xn,
                      float* __restrict__ hn_f32, unsigned short* __restrict__ hn_bf,
                      unsigned short* __restrict__ rh_bf, float* __restrict__ z_f32,
                      float* __restrict__ states, unsigned short* __restrict__ states_bf,
                      unsigned* bar)
{
    __shared__ float red_s[16][8];
    __shared__ float red_q[16][8];
    const int b    = blockIdx.x;
    const int wave = threadIdx.x >> 6;
    const int lane = threadIdx.x & 63;
    const int lhi  = lane >> 4;
    const int llo  = lane & 15;
    unsigned target = 0;

    for (int t = 0; t < TT; ++t) {
        const unsigned short* xn_t = xn + (size_t)(t & 1) * BB * 512;

        // ---------------- PHASE A ----------------
        {
            const int m0 = (b >> 3) * 64 + (wave >> 2) * 32;
            const int n0 = (b & 7) * 128 + (wave & 3) * 32;
            f32x4 acc[2][2] = {};
#pragma unroll
            for (int seg = 0; seg < 2; ++seg) {
                const unsigned short* Ab = seg ? hn_bf : xn_t;
#pragma unroll 2
                for (int k0 = 0; k0 < 512; k0 += 32) {
                    const int kk = k0 + lhi * 8;
                    short8 a0 = *(const short8*)(Ab + (size_t)(m0 + llo) * 512 + kk);
                    short8 a1 = *(const short8*)(Ab + (size_t)(m0 + 16 + llo) * 512 + kk);
                    short8 w0 = *(const short8*)(Wrz + (size_t)(n0 + llo) * 1024 + seg * 512 + kk);
                    short8 w1 = *(const short8*)(Wrz + (size_t)(n0 + 16 + llo) * 1024 + seg * 512 + kk);
                    acc[0][0] = __builtin_amdgcn_mfma_f32_16x16x32_bf16(a0, w0, acc[0][0], 0, 0, 0);
                    acc[0][1] = __builtin_amdgcn_mfma_f32_16x16x32_bf16(a0, w1, acc[0][1], 0, 0, 0);
                    acc[1][0] = __builtin_amdgcn_mfma_f32_16x16x32_bf16(a1, w0, acc[1][0], 0, 0, 0);
                    acc[1][1] = __builtin_amdgcn_mfma_f32_16x16x32_bf16(a1, w1, acc[1][1], 0, 0, 0);
                }
            }
            const bool is_r = (n0 < 512);
#pragma unroll
            for (int mf = 0; mf < 2; ++mf)
#pragma unroll
                for (int i = 0; i < 4; ++i) {
                    const int row = m0 + mf * 16 + lhi * 4 + i;
#pragma unroll
                    for (int nf = 0; nf < 2; ++nf) {
                        const int col = n0 + nf * 16 + llo;
                        const float v  = acc[mf][nf][i] + (is_r ? br[col] : bz[col - 512]);
                        const float sg = sigmoidf_(v);
                        if (is_r)
                            rh_bf[(size_t)row * 512 + col] = f2bf(sg * hn_f32[(size_t)row * 512 + col]);
                        else
                            z_f32[(size_t)row * 512 + (col - 512)] = sg;
                    }
                }
        }
        target += NBLK; gsync(bar, target);

        // ---------------- PHASE B ----------------
        if (b < 128) {
            const int m0 = b * 16;
            const int c0 = wave * 64;
            f32x4 acc[4] = {};
#pragma unroll
            for (int seg = 0; seg < 2; ++seg) {
                const unsigned short* Ab = seg ? rh_bf : xn_t;
#pragma unroll 2
                for (int k0 = 0; k0 < 512; k0 += 32) {
                    const int kk = k0 + lhi * 8;
                    short8 a = *(const short8*)(Ab + (size_t)(m0 + llo) * 512 + kk);
#pragma unroll
                    for (int nf = 0; nf < 4; ++nf) {
                        short8 w = *(const short8*)(Wc + (size_t)(c0 + nf * 16 + llo) * 1024 + seg * 512 + kk);
                        acc[nf] = __builtin_amdgcn_mfma_f32_16x16x32_bf16(a, w, acc[nf], 0, 0, 0);
                    }
                }
            }
            // h_new = (1-z)*hn + z*tanh(acc + bc)
#pragma unroll
            for (int nf = 0; nf < 4; ++nf)
#pragma unroll
                for (int i = 0; i < 4; ++i) {
                    const int row = m0 + lhi * 4 + i;
                    const int col = c0 + nf * 16 + llo;
                    const size_t off = (size_t)row * 512 + col;
                    const float htil = tanhf_(acc[nf][i] + bc[col]);
                    const float z = z_f32[off];
                    acc[nf][i] = (1.0f - z) * hn_f32[off] + z * htil;
                }
            // LN1 (cell)
            float mu[4], rsd[4];
#pragma unroll
            for (int i = 0; i < 4; ++i) {
                float s = acc[0][i] + acc[1][i] + acc[2][i] + acc[3][i];
                float q = acc[0][i]*acc[0][i] + acc[1][i]*acc[1][i]
                        + acc[2][i]*acc[2][i] + acc[3][i]*acc[3][i];
#pragma unroll
                for (int m = 8; m >= 1; m >>= 1) { s += __shfl_xor(s, m); q += __shfl_xor(q, m); }
                if (llo == 0) { red_s[lhi * 4 + i][wave] = s; red_q[lhi * 4 + i][wave] = q; }
            }
            __syncthreads();
#pragma unroll
            for (int i = 0; i < 4; ++i) {
                float s = 0.f, q = 0.f;
#pragma unroll
                for (int w2 = 0; w2 < 8; ++w2) { s += red_s[lhi * 4 + i][w2]; q += red_q[lhi * 4 + i][w2]; }
                const float m_ = s * (1.0f / 512.0f);
                mu[i]  = m_;
                rsd[i] = rsqrtf(q * (1.0f / 512.0f) - m_ * m_ + 1e-5f);
            }
#pragma unroll
            for (int nf = 0; nf < 4; ++nf)
#pragma unroll
                for (int i = 0; i < 4; ++i) {
                    const int row = m0 + lhi * 4 + i;
                    const int col = c0 + nf * 16 + llo;
                    const size_t off = (size_t)row * 512 + col;
                    const float h = (acc[nf][i] - mu[i]) * rsd[i] * gc[col] + bcl[col];
                    states[(size_t)t * BB * 512 + off] = h;
                    if (states_bf) states_bf[(size_t)t * BB * 512 + off] = f2bf(h);
                    acc[nf][i] = h;
                }
            if (t + 1 < TT) {
                __syncthreads();
                // LN2 (h) * exp(-dt)
#pragma unroll
                for (int i = 0; i < 4; ++i) {
                    float s = acc[0][i] + acc[1][i] + acc[2][i] + acc[3][i];
                    float q = acc[0][i]*acc[0][i] + acc[1][i]*acc[1][i]
                            + acc[2][i]*acc[2][i] + acc[3][i]*acc[3][i];
#pragma unroll
                    for (int m = 8; m >= 1; m >>= 1) { s += __shfl_xor(s, m); q += __shfl_xor(q, m); }
                    if (llo == 0) { red_s[lhi * 4 + i][wave] = s; red_q[lhi * 4 + i][wave] = q; }
                }
                __syncthreads();
                float dec_[4];
#pragma unroll
                for (int i = 0; i < 4; ++i) {
                    float s = 0.f, q = 0.f;
#pragma unroll
                    for (int w2 = 0; w2 < 8; ++w2) { s += red_s[lhi * 4 + i][w2]; q += red_q[lhi * 4 + i][w2]; }
                    const float m_ = s * (1.0f / 512.0f);
                    mu[i]  = m_;
                    rsd[i] = rsqrtf(q * (1.0f / 512.0f) - m_ * m_ + 1e-5f);
                    const int row = m0 + lhi * 4 + i;
                    float dtv = ts[(size_t)row * TT + t + 1] - ts[(size_t)row * TT + t];
                    dtv = fminf(fmaxf(dtv, 0.0f), 10.0f);
                    dec_[i] = expf(-dtv);
                }
#pragma unroll
                for (int nf = 0; nf < 4; ++nf)
#pragma unroll
                    for (int i = 0; i < 4; ++i) {
                        const int row = m0 + lhi * 4 + i;
                        const int col = c0 + nf * 16 + llo;
                        const size_t off = (size_t)row * 512 + col;
                        const float hnv = ((acc[nf][i] - mu[i]) * rsd[i] * gh[col] + bh[col]) * dec_[i];
                        hn_f32[off] = hnv;
                        hn_bf[off]  = f2bf(hnv);
                    }
            }
        } else if (t + 1 < TT) {
            // xn for step t+1
            const int m0 = (b - 128) * 16;
            const float* sq = seq + (size_t)(t + 1) * BB * 512;
            unsigned short* xo = xn + (size_t)((t + 1) & 1) * BB * 512;
#pragma unroll
            for (int rr = 0; rr < 2; ++rr) {
                const int row = m0 + wave + rr * 8;
                ln_row_wave(sq + (size_t)row * 512, gx, bx, xo + (size_t)row * 512, lane);
            }
        }
        target += NBLK; gsync(bar, target);
    }
}

// ---------------- final projection + residual + LN (in-place safe) ----------------
template<int BF>
__global__ __launch_bounds__(512)
void proj_kernel(const float* __restrict__ S, const unsigned short* __restrict__ Sb,
                 const unsigned short* __restrict__ Wo, const float* __restrict__ bo,
                 const float* __restrict__ seq, const float* __restrict__ gf,
                 const float* __restrict__ bff, float* __restrict__ out)
{
    const int tid  = threadIdx.x;
    const int wave = tid >> 6;
    const int lane = tid & 63;
    const int lhi  = lane >> 4;
    const int llo  = lane & 15;
    const long m0  = (long)blockIdx.x * 64;

    f32x4 acc[4][4] = {};
    for (int k0 = 0; k0 < 512; k0 += 32) {
        const int kk = k0 + lhi * 8;
        short8 a[4], b[4];
#pragma unroll
        for (int mf = 0; mf < 4; ++mf) {
            if (BF) {
                a[mf] = *(const short8*)(Sb + (size_t)(m0 + mf * 16 + llo) * 512 + kk);
            } else {
                const float* ap = S + (size_t)(m0 + mf * 16 + llo) * 512 + kk;
                float4 f0 = *(const float4*)ap;
                float4 f1 = *(const float4*)(ap + 4);
                short8 av;
                av[0] = (short)f2bf(f0.x); av[1] = (short)f2bf(f0.y);
                av[2] = (short)f2bf(f0.z); av[3] = (short)f2bf(f0.w);
                av[4] = (short)f2bf(f1.x); av[5] = (short)f2bf(f1.y);
                av[6] = (short)f2bf(f1.z); av[7] = (short)f2bf(f1.w);
                a[mf] = av;
            }
        }
#pragma unroll
        for (int nf = 0; nf < 4; ++nf)
            b[nf] = *(const short8*)(Wo + (size_t)(wave * 64 + nf * 16 + llo) * 512 + kk);
#pragma unroll
        for (int mf = 0; mf < 4; ++mf)
#pragma unroll
            for (int nf = 0; nf < 4; ++nf)
                acc[mf][nf] = __builtin_amdgcn_mfma_f32_16x16x32_bf16(a[mf], b[nf], acc[mf][nf], 0, 0, 0);
    }

    __shared__ float red_s[64][8];
    __shared__ float red_q[64][8];

#pragma unroll
    for (int mf = 0; mf < 4; ++mf)
#pragma unroll
        for (int i = 0; i < 4; ++i) {
            const long row = m0 + mf * 16 + lhi * 4 + i;
#pragma unroll
            for (int nf = 0; nf < 4; ++nf) {
                const int col = wave * 64 + nf * 16 + llo;
                acc[mf][nf][i] += bo[col] + seq[(size_t)row * 512 + col];
            }
        }
    float mu[4][4], rstd[4][4];
#pragma unroll
    for (int mf = 0; mf < 4; ++mf)
#pragma unroll
        for (int i = 0; i < 4; ++i) {
            float s = 0.f, q = 0.f;
#pragma unroll
            for (int nf = 0; nf < 4; ++nf) { const float v = acc[mf][nf][i]; s += v; q += v * v; }
#pragma unroll
            for (int m = 8; m >= 1; m >>= 1) { s += __shfl_xor(s, m); q += __shfl_xor(q, m); }
            if (llo == 0) { red_s[mf * 16 + lhi * 4 + i][wave] = s; red_q[mf * 16 + lhi * 4 + i][wave] = q; }
        }
    __syncthreads();
#pragma unroll
    for (int mf = 0; mf < 4; ++mf)
#pragma unroll
        for (int i = 0; i < 4; ++i) {
            const int rl = mf * 16 + lhi * 4 + i;
            float s = 0.f, q = 0.f;
#pragma unroll
            for (int w2 = 0; w2 < 8; ++w2) { s += red_s[rl][w2]; q += red_q[rl][w2]; }
            const float m_ = s * (1.0f / 512.0f);
            const float var = q * (1.0f / 512.0f) - m_ * m_;
            mu[mf][i] = m_;
            rstd[mf][i] = rsqrtf(var + 1e-5f);
        }
#pragma unroll
    for (int mf = 0; mf < 4; ++mf)
#pragma unroll
        for (int i = 0; i < 4; ++i) {
            const long row = m0 + mf * 16 + lhi * 4 + i;
#pragma unroll
            for (int nf = 0; nf < 4; ++nf) {
                const int col = wave * 64 + nf * 16 + llo;
                out[(size_t)row * 512 + col] = (acc[mf][nf][i] - mu[mf][i]) * rstd[mf][i] * gf[col] + bff[col];
            }
        }
}

extern "C" void kernel_launch(void* const* d_in, const int* in_sizes, int n_in,
                              void* d_out, int out_size, void* d_ws, size_t ws_size,
                              hipStream_t stream) {
    const float* seq = (const float*)d_in[0];
    const float* ts  = (const float*)d_in[1];
    const float* Wr  = (const float*)d_in[2];
    const float* br  = (const float*)d_in[3];
    const float* Wz  = (const float*)d_in[4];
    const float* bz  = (const float*)d_in[5];
    const float* Wc  = (const float*)d_in[6];
    const float* bc  = (const float*)d_in[7];
    const float* Wo  = (const float*)d_in[8];
    const float* bo  = (const float*)d_in[9];
    const float* gx  = (const float*)d_in[10];
    const float* bx  = (const float*)d_in[11];
    const float* gh  = (const float*)d_in[12];
    const float* bh  = (const float*)d_in[13];
    const float* gc  = (const float*)d_in[14];
    const float* bcl = (const float*)d_in[15];
    const float* gf  = (const float*)d_in[16];
    const float* bf  = (const float*)d_in[17];
    float* out = (float*)d_out;

    char* w = (char*)d_ws;
    unsigned* bar = (unsigned*)w;               w += 256;
    float* hn_f32 = (float*)w;                  w += (size_t)BB * 512 * 4;
    float* z_f32  = (float*)w;                  w += (size_t)BB * 512 * 4;
    unsigned short* rh_bf = (unsigned short*)w; w += (size_t)BB * 512 * 2;
    unsigned short* hn_bf = (unsigned short*)w; w += (size_t)BB * 512 * 2;
    unsigned short* xn    = (unsigned short*)w; w += (size_t)2 * BB * 512 * 2;
    unsigned short* Wrz_b = (unsigned short*)w; w += (size_t)1024 * 1024 * 2;
    unsigned short* Wc_b  = (unsigned short*)w; w += (size_t)512 * 1024 * 2;
    unsigned short* Wo_b  = (unsigned short*)w; w += (size_t)512 * 512 * 2;
    unsigned short* states_bf = (unsigned short*)w;
    const size_t fixed = (size_t)(w - (char*)d_ws);
    const bool sbf = ws_size >= fixed + (size_t)TT * BB * 512 * 2;

    hipMemsetAsync(bar, 0, 256, stream);
    hipMemsetAsync(hn_f32, 0, (size_t)BB * 512 * 4, stream);
    hipMemsetAsync(hn_bf, 0, (size_t)BB * 512 * 2, stream);

    cvt_kernel<<<(512 * 1024 + 255) / 256, 256, 0, stream>>>(Wr, Wrz_b, 512 * 1024);
    cvt_kernel<<<(512 * 1024 + 255) / 256, 256, 0, stream>>>(Wz, Wrz_b + (size_t)512 * 1024, 512 * 1024);
    cvt_kernel<<<(512 * 1024 + 255) / 256, 256, 0, stream>>>(Wc, Wc_b, 512 * 1024);
    cvt_kernel<<<(512 * 512 + 255) / 256, 256, 0, stream>>>(Wo, Wo_b, 512 * 512);

    ln_x_kernel<<<BB / 4, 256, 0, stream>>>(seq, gx, bx, xn);

    recurrent_kernel<<<NBLK, 512, 0, stream>>>(seq, ts, Wrz_b, Wc_b, br, bz, bc,
                                               gx, bx, gh, bh, gc, bcl,
                                               xn, hn_f32, hn_bf, rh_bf, z_f32,
                                               out, sbf ? states_bf : nullptr, bar);

    if (sbf)
        proj_kernel<1><<<2048, 512, 0, stream>>>(out, states_bf, Wo_b, bo, seq, gf, bf, out);
    else
        proj_kernel<0><<<2048, 512, 0, stream>>>(out, nullptr, Wo_b, bo, seq, gf, bf, out);
}

// Round 4
// 2378.968 us; speedup vs baseline: 6.6842x; 6.6842x over previous
//
#include <hip/hip_runtime.h>
#include <math.h>

#define TT 64
#define BB 2048

using f32x4  = __attribute__((ext_vector_type(4))) float;
using short8 = __attribute__((ext_vector_type(8))) short;

__device__ __forceinline__ unsigned short f2bf(float f) {
    unsigned u = __float_as_uint(f);
    u += 0x7FFF + ((u >> 16) & 1);
    return (unsigned short)(u >> 16);
}
__device__ __forceinline__ float bf2f(unsigned short h) {
    unsigned u = ((unsigned)h) << 16;
    return __uint_as_float(u);
}
__device__ __forceinline__ float sigmoidf_(float v) { return 1.0f / (1.0f + expf(-v)); }
__device__ __forceinline__ float tanhf_(float v)    { return 1.0f - 2.0f / (expf(2.0f * v) + 1.0f); }

// plain f32 -> bf16 (for Wo, proj keeps row-major layout)
__global__ __launch_bounds__(256)
void cvt_kernel(const float* __restrict__ src, unsigned short* __restrict__ dst, int n) {
    int i = blockIdx.x * 256 + threadIdx.x;
    if (i < n) dst[i] = f2bf(src[i]);
}

// pack W[N][K] (row-major) into MFMA fragment order:
// dst[((nf*(K/32) + ks)*64 + lane)*8 + j] = W[nf*16 + (lane&15)][ks*32 + (lane>>4)*8 + j]
__global__ __launch_bounds__(256)
void pack_w(const float* __restrict__ src, unsigned short* __restrict__ dst, int N, int K) {
    int i = blockIdx.x * 256 + threadIdx.x;
    if (i >= N * K) return;
    int n = i / K, k = i - n * K;
    int nf = n >> 4, llo = n & 15;
    int ks = k >> 5, khi = (k >> 3) & 3, j = k & 7;
    size_t dstIdx = (((size_t)nf * (K >> 5) + ks) * 64 + (khi * 16 + llo)) * 8 + j;
    dst[dstIdx] = f2bf(src[i]);
}

// packed index inside a [16 rows][512 cols] LDS tile (fragment order)
__device__ __forceinline__ int pk_idx(int row, int col) {
    int ks = col >> 5, khi = (col >> 3) & 3, j = col & 7;
    return ((ks * 64) + khi * 16 + row) * 8 + j;
}

// LN one 512-wide row -> packed bf16 LDS tile
__device__ __forceinline__ void ln_row_pk(const float* __restrict__ xr,
                                          const float* __restrict__ g,
                                          const float* __restrict__ b,
                                          unsigned short* __restrict__ tile,
                                          int row, int lane) {
    const int c0 = lane * 8;
    float4 v0 = *(const float4*)(xr + c0);
    float4 v1 = *(const float4*)(xr + c0 + 4);
    float s  = v0.x + v0.y + v0.z + v0.w + v1.x + v1.y + v1.z + v1.w;
    float ss = v0.x*v0.x + v0.y*v0.y + v0.z*v0.z + v0.w*v0.w
             + v1.x*v1.x + v1.y*v1.y + v1.z*v1.z + v1.w*v1.w;
#pragma unroll
    for (int m = 32; m > 0; m >>= 1) { s += __shfl_xor(s, m); ss += __shfl_xor(ss, m); }
    const float mean = s * (1.0f / 512.0f);
    const float var  = ss * (1.0f / 512.0f) - mean * mean;
    const float rs   = rsqrtf(var + 1e-5f);
    float4 g0 = *(const float4*)(g + c0);
    float4 g1 = *(const float4*)(g + c0 + 4);
    float4 b0 = *(const float4*)(b + c0);
    float4 b1 = *(const float4*)(b + c0 + 4);
    short8 o;
    o[0] = (short)f2bf((v0.x - mean) * rs * g0.x + b0.x);
    o[1] = (short)f2bf((v0.y - mean) * rs * g0.y + b0.y);
    o[2] = (short)f2bf((v0.z - mean) * rs * g0.z + b0.z);
    o[3] = (short)f2bf((v0.w - mean) * rs * g0.w + b0.w);
    o[4] = (short)f2bf((v1.x - mean) * rs * g1.x + b1.x);
    o[5] = (short)f2bf((v1.y - mean) * rs * g1.y + b1.y);
    o[6] = (short)f2bf((v1.z - mean) * rs * g1.z + b1.z);
    o[7] = (short)f2bf((v1.w - mean) * rs * g1.w + b1.w);
    // col block c0=lane*8: ks=lane>>2, khi=lane&3, j=0..7
    *(short8*)&tile[(((lane >> 2) * 64) + (lane & 3) * 16 + row) * 8] = o;
}

// ---------------- block-local persistent recurrence ----------------
// 128 blocks x 512 threads; block owns rows m0..m0+15 for ALL timesteps.
// No grid sync. Weights streamed from L2 in fragment-packed layout.
template<int SBF>
__global__ __launch_bounds__(512)
void recurrent_kernel(const float* __restrict__ seq, const float* __restrict__ ts,
                      const unsigned short* __restrict__ Wrz, const unsigned short* __restrict__ Wc,
                      const float* __restrict__ br, const float* __restrict__ bz,
                      const float* __restrict__ bc,
                      const float* __restrict__ gx, const float* __restrict__ bx,
                      const float* __restrict__ gh, const float* __restrict__ bh,
                      const float* __restrict__ gc, const float* __restrict__ bcl,
                      float* __restrict__ states_f32, unsigned short* __restrict__ states_bf)
{
    __shared__ unsigned short xn_s[16 * 512];
    __shared__ unsigned short hn_s[16 * 512];
    __shared__ unsigned short rh_s[16 * 512];
    __shared__ float red_s[16][8];
    __shared__ float red_q[16][8];

    const int tid  = threadIdx.x;
    const int w    = tid >> 6;
    const int lane = tid & 63;
    const int lhi  = lane >> 4;
    const int llo  = lane & 15;
    const int m0   = blockIdx.x * 16;

    // zero hn tile
    for (int i = tid; i < 1024; i += 512) *(short8*)&hn_s[i * 8] = short8{};
    // xn(0)
#pragma unroll
    for (int rr = 0; rr < 2; ++rr) {
        const int r = w * 2 + rr;
        ln_row_pk(seq + (size_t)(m0 + r) * 512, gx, bx, xn_s, r, lane);
    }
    __syncthreads();

    float zreg[4][4];

    for (int t = 0; t < TT; ++t) {
        // ---------- rz GEMM: wave w -> r cols [w*64..], z cols [w*64..] ----------
        {
            f32x4 aR[4] = {}, aZ[4] = {};
            const unsigned short* wrb = Wrz + (size_t)(w * 4) * 16384;
            const unsigned short* wzb = Wrz + (size_t)(32 + w * 4) * 16384;
#pragma unroll 4
            for (int ks = 0; ks < 16; ++ks) {
                short8 a = *(const short8*)&xn_s[(ks * 64 + lane) * 8];
                const int off = ks * 512 + lane * 8;
#pragma unroll
                for (int f = 0; f < 4; ++f) {
                    short8 b1 = *(const short8*)(wrb + (size_t)f * 16384 + off);
                    aR[f] = __builtin_amdgcn_mfma_f32_16x16x32_bf16(a, b1, aR[f], 0, 0, 0);
                    short8 b2 = *(const short8*)(wzb + (size_t)f * 16384 + off);
                    aZ[f] = __builtin_amdgcn_mfma_f32_16x16x32_bf16(a, b2, aZ[f], 0, 0, 0);
                }
            }
#pragma unroll 4
            for (int ks = 16; ks < 32; ++ks) {
                short8 a = *(const short8*)&hn_s[((ks - 16) * 64 + lane) * 8];
                const int off = ks * 512 + lane * 8;
#pragma unroll
                for (int f = 0; f < 4; ++f) {
                    short8 b1 = *(const short8*)(wrb + (size_t)f * 16384 + off);
                    aR[f] = __builtin_amdgcn_mfma_f32_16x16x32_bf16(a, b1, aR[f], 0, 0, 0);
                    short8 b2 = *(const short8*)(wzb + (size_t)f * 16384 + off);
                    aZ[f] = __builtin_amdgcn_mfma_f32_16x16x32_bf16(a, b2, aZ[f], 0, 0, 0);
                }
            }
            // epilogue: r -> rh (LDS), z -> regs
#pragma unroll
            for (int f = 0; f < 4; ++f)
#pragma unroll
                for (int i = 0; i < 4; ++i) {
                    const int row = lhi * 4 + i;
                    const int col = w * 64 + f * 16 + llo;
                    const float rr = sigmoidf_(aR[f][i] + br[col]);
                    const float hv = bf2f(hn_s[pk_idx(row, col)]);
                    rh_s[pk_idx(row, col)] = f2bf(rr * hv);
                    zreg[f][i] = sigmoidf_(aZ[f][i] + bz[col]);
                }
        }
        __syncthreads();   // rh ready

        // ---------- c GEMM ----------
        f32x4 aC[4] = {};
        {
            const unsigned short* wcb = Wc + (size_t)(w * 4) * 16384;
#pragma unroll 4
            for (int ks = 0; ks < 16; ++ks) {
                short8 a = *(const short8*)&xn_s[(ks * 64 + lane) * 8];
                const int off = ks * 512 + lane * 8;
#pragma unroll
                for (int f = 0; f < 4; ++f) {
                    short8 b1 = *(const short8*)(wcb + (size_t)f * 16384 + off);
                    aC[f] = __builtin_amdgcn_mfma_f32_16x16x32_bf16(a, b1, aC[f], 0, 0, 0);
                }
            }
#pragma unroll 4
            for (int ks = 16; ks < 32; ++ks) {
                short8 a = *(const short8*)&rh_s[((ks - 16) * 64 + lane) * 8];
                const int off = ks * 512 + lane * 8;
#pragma unroll
                for (int f = 0; f < 4; ++f) {
                    short8 b1 = *(const short8*)(wcb + (size_t)f * 16384 + off);
                    aC[f] = __builtin_amdgcn_mfma_f32_16x16x32_bf16(a, b1, aC[f], 0, 0, 0);
                }
            }
        }
        __syncthreads();   // all LDS reads of xn/rh done

        // ---------- epilogue: blend, LN_cell -> states, LN_h*exp(-dt) -> hn ----------
        {
            float hnew[4][4];
#pragma unroll
            for (int f = 0; f < 4; ++f)
#pragma unroll
                for (int i = 0; i < 4; ++i) {
                    const int row = lhi * 4 + i;
                    const int col = w * 64 + f * 16 + llo;
                    const float htil = tanhf_(aC[f][i] + bc[col]);
                    const float hv = bf2f(hn_s[pk_idx(row, col)]);
                    const float z = zreg[f][i];
                    hnew[f][i] = (1.0f - z) * hv + z * htil;
                }
            // LN1 stats
#pragma unroll
            for (int i = 0; i < 4; ++i) {
                float s = hnew[0][i] + hnew[1][i] + hnew[2][i] + hnew[3][i];
                float q = hnew[0][i]*hnew[0][i] + hnew[1][i]*hnew[1][i]
                        + hnew[2][i]*hnew[2][i] + hnew[3][i]*hnew[3][i];
#pragma unroll
                for (int m = 8; m >= 1; m >>= 1) { s += __shfl_xor(s, m); q += __shfl_xor(q, m); }
                if (llo == 0) { red_s[lhi * 4 + i][w] = s; red_q[lhi * 4 + i][w] = q; }
            }
            __syncthreads();
            float mu[4], rsd[4];
#pragma unroll
            for (int i = 0; i < 4; ++i) {
                float s = 0.f, q = 0.f;
#pragma unroll
                for (int w2 = 0; w2 < 8; ++w2) { s += red_s[lhi * 4 + i][w2]; q += red_q[lhi * 4 + i][w2]; }
                const float m_ = s * (1.0f / 512.0f);
                mu[i]  = m_;
                rsd[i] = rsqrtf(q * (1.0f / 512.0f) - m_ * m_ + 1e-5f);
            }
            // states write, keep LN1(h) in hnew
#pragma unroll
            for (int f = 0; f < 4; ++f)
#pragma unroll
                for (int i = 0; i < 4; ++i) {
                    const int row = lhi * 4 + i;
                    const int col = w * 64 + f * 16 + llo;
                    const float h = (hnew[f][i] - mu[i]) * rsd[i] * gc[col] + bcl[col];
                    const size_t off = (size_t)t * BB * 512 + (size_t)(m0 + row) * 512 + col;
                    if (SBF) states_bf[off] = f2bf(h);
                    else     states_f32[off] = h;
                    hnew[f][i] = h;
                }
            if (t + 1 < TT) {
                __syncthreads();   // red_s reuse
                // LN2 stats
#pragma unroll
                for (int i = 0; i < 4; ++i) {
                    float s = hnew[0][i] + hnew[1][i] + hnew[2][i] + hnew[3][i];
                    float q = hnew[0][i]*hnew[0][i] + hnew[1][i]*hnew[1][i]
                            + hnew[2][i]*hnew[2][i] + hnew[3][i]*hnew[3][i];
#pragma unroll
                    for (int m = 8; m >= 1; m >>= 1) { s += __shfl_xor(s, m); q += __shfl_xor(q, m); }
                    if (llo == 0) { red_s[lhi * 4 + i][w] = s; red_q[lhi * 4 + i][w] = q; }
                }
                __syncthreads();
                float dec_[4];
#pragma unroll
                for (int i = 0; i < 4; ++i) {
                    float s = 0.f, q = 0.f;
#pragma unroll
                    for (int w2 = 0; w2 < 8; ++w2) { s += red_s[lhi * 4 + i][w2]; q += red_q[lhi * 4 + i][w2]; }
                    const float m_ = s * (1.0f / 512.0f);
                    mu[i]  = m_;
                    rsd[i] = rsqrtf(q * (1.0f / 512.0f) - m_ * m_ + 1e-5f);
                    const int row = m0 + lhi * 4 + i;
                    float dtv = ts[(size_t)row * TT + t + 1] - ts[(size_t)row * TT + t];
                    dtv = fminf(fmaxf(dtv, 0.0f), 10.0f);
                    dec_[i] = expf(-dtv);
                }
#pragma unroll
                for (int f = 0; f < 4; ++f)
#pragma unroll
                    for (int i = 0; i < 4; ++i) {
                        const int row = lhi * 4 + i;
                        const int col = w * 64 + f * 16 + llo;
                        const float hv = ((hnew[f][i] - mu[i]) * rsd[i] * gh[col] + bh[col]) * dec_[i];
                        hn_s[pk_idx(row, col)] = f2bf(hv);
                    }
                // xn(t+1)
#pragma unroll
                for (int rr = 0; rr < 2; ++rr) {
                    const int r = w * 2 + rr;
                    ln_row_pk(seq + ((size_t)(t + 1) * BB + m0 + r) * 512, gx, bx, xn_s, r, lane);
                }
            }
        }
        __syncthreads();   // hn/xn ready for next step
    }
}

// ---------------- final projection + residual + LN (in-place safe) ----------------
template<int BF>
__global__ __launch_bounds__(512)
void proj_kernel(const float* __restrict__ S, const unsigned short* __restrict__ Sb,
                 const unsigned short* __restrict__ Wo, const float* __restrict__ bo,
                 const float* __restrict__ seq, const float* __restrict__ gf,
                 const float* __restrict__ bff, float* __restrict__ out)
{
    const int tid  = threadIdx.x;
    const int wave = tid >> 6;
    const int lane = tid & 63;
    const int lhi  = lane >> 4;
    const int llo  = lane & 15;
    const long m0  = (long)blockIdx.x * 64;

    f32x4 acc[4][4] = {};
    for (int k0 = 0; k0 < 512; k0 += 32) {
        const int kk = k0 + lhi * 8;
        short8 a[4], b[4];
#pragma unroll
        for (int mf = 0; mf < 4; ++mf) {
            if (BF) {
                a[mf] = *(const short8*)(Sb + (size_t)(m0 + mf * 16 + llo) * 512 + kk);
            } else {
                const float* ap = S + (size_t)(m0 + mf * 16 + llo) * 512 + kk;
                float4 f0 = *(const float4*)ap;
                float4 f1 = *(const float4*)(ap + 4);
                short8 av;
                av[0] = (short)f2bf(f0.x); av[1] = (short)f2bf(f0.y);
                av[2] = (short)f2bf(f0.z); av[3] = (short)f2bf(f0.w);
                av[4] = (short)f2bf(f1.x); av[5] = (short)f2bf(f1.y);
                av[6] = (short)f2bf(f1.z); av[7] = (short)f2bf(f1.w);
                a[mf] = av;
            }
        }
#pragma unroll
        for (int nf = 0; nf < 4; ++nf)
            b[nf] = *(const short8*)(Wo + (size_t)(wave * 64 + nf * 16 + llo) * 512 + kk);
#pragma unroll
        for (int mf = 0; mf < 4; ++mf)
#pragma unroll
            for (int nf = 0; nf < 4; ++nf)
                acc[mf][nf] = __builtin_amdgcn_mfma_f32_16x16x32_bf16(a[mf], b[nf], acc[mf][nf], 0, 0, 0);
    }

    __shared__ float red_s[64][8];
    __shared__ float red_q[64][8];

#pragma unroll
    for (int mf = 0; mf < 4; ++mf)
#pragma unroll
        for (int i = 0; i < 4; ++i) {
            const long row = m0 + mf * 16 + lhi * 4 + i;
#pragma unroll
            for (int nf = 0; nf < 4; ++nf) {
                const int col = wave * 64 + nf * 16 + llo;
                acc[mf][nf][i] += bo[col] + seq[(size_t)row * 512 + col];
            }
        }
    float mu[4][4], rstd[4][4];
#pragma unroll
    for (int mf = 0; mf < 4; ++mf)
#pragma unroll
        for (int i = 0; i < 4; ++i) {
            float s = 0.f, q = 0.f;
#pragma unroll
            for (int nf = 0; nf < 4; ++nf) { const float v = acc[mf][nf][i]; s += v; q += v * v; }
#pragma unroll
            for (int m = 8; m >= 1; m >>= 1) { s += __shfl_xor(s, m); q += __shfl_xor(q, m); }
            if (llo == 0) { red_s[mf * 16 + lhi * 4 + i][wave] = s; red_q[mf * 16 + lhi * 4 + i][wave] = q; }
        }
    __syncthreads();
#pragma unroll
    for (int mf = 0; mf < 4; ++mf)
#pragma unroll
        for (int i = 0; i < 4; ++i) {
            const int rl = mf * 16 + lhi * 4 + i;
            float s = 0.f, q = 0.f;
#pragma unroll
            for (int w2 = 0; w2 < 8; ++w2) { s += red_s[rl][w2]; q += red_q[rl][w2]; }
            const float m_ = s * (1.0f / 512.0f);
            const float var = q * (1.0f / 512.0f) - m_ * m_;
            mu[mf][i] = m_;
            rstd[mf][i] = rsqrtf(var + 1e-5f);
        }
#pragma unroll
    for (int mf = 0; mf < 4; ++mf)
#pragma unroll
        for (int i = 0; i < 4; ++i) {
            const long row = m0 + mf * 16 + lhi * 4 + i;
#pragma unroll
            for (int nf = 0; nf < 4; ++nf) {
                const int col = wave * 64 + nf * 16 + llo;
                out[(size_t)row * 512 + col] = (acc[mf][nf][i] - mu[mf][i]) * rstd[mf][i] * gf[col] + bff[col];
            }
        }
}

extern "C" void kernel_launch(void* const* d_in, const int* in_sizes, int n_in,
                              void* d_out, int out_size, void* d_ws, size_t ws_size,
                              hipStream_t stream) {
    const float* seq = (const float*)d_in[0];
    const float* ts  = (const float*)d_in[1];
    const float* Wr  = (const float*)d_in[2];
    const float* br  = (const float*)d_in[3];
    const float* Wz  = (const float*)d_in[4];
    const float* bz  = (const float*)d_in[5];
    const float* Wc  = (const float*)d_in[6];
    const float* bc  = (const float*)d_in[7];
    const float* Wo  = (const float*)d_in[8];
    const float* bo  = (const float*)d_in[9];
    const float* gx  = (const float*)d_in[10];
    const float* bx  = (const float*)d_in[11];
    const float* gh  = (const float*)d_in[12];
    const float* bh  = (const float*)d_in[13];
    const float* gc  = (const float*)d_in[14];
    const float* bcl = (const float*)d_in[15];
    const float* gf  = (const float*)d_in[16];
    const float* bf  = (const float*)d_in[17];
    float* out = (float*)d_out;

    char* w = (char*)d_ws;
    unsigned short* Wrz_pk = (unsigned short*)w; w += (size_t)1024 * 1024 * 2;
    unsigned short* Wc_pk  = (unsigned short*)w; w += (size_t)512 * 1024 * 2;
    unsigned short* Wo_b   = (unsigned short*)w; w += (size_t)512 * 512 * 2;
    unsigned short* states_bf = (unsigned short*)w;
    const size_t fixed = (size_t)(w - (char*)d_ws);
    const bool sbf = ws_size >= fixed + (size_t)TT * BB * 512 * 2;

    pack_w<<<(512 * 1024 + 255) / 256, 256, 0, stream>>>(Wr, Wrz_pk, 512, 1024);
    pack_w<<<(512 * 1024 + 255) / 256, 256, 0, stream>>>(Wz, Wrz_pk + (size_t)512 * 1024, 512, 1024);
    pack_w<<<(512 * 1024 + 255) / 256, 256, 0, stream>>>(Wc, Wc_pk, 512, 1024);
    cvt_kernel<<<(512 * 512 + 255) / 256, 256, 0, stream>>>(Wo, Wo_b, 512 * 512);

    if (sbf) {
        recurrent_kernel<1><<<128, 512, 0, stream>>>(seq, ts, Wrz_pk, Wc_pk, br, bz, bc,
                                                     gx, bx, gh, bh, gc, bcl, out, states_bf);
        proj_kernel<1><<<2048, 512, 0, stream>>>(nullptr, states_bf, Wo_b, bo, seq, gf, bf, out);
    } else {
        recurrent_kernel<0><<<128, 512, 0, stream>>>(seq, ts, Wrz_pk, Wc_pk, br, bz, bc,
                                                     gx, bx, gh, bh, gc, bcl, out, states_bf);
        proj_kernel<0><<<2048, 512, 0, stream>>>(out, nullptr, Wo_b, bo, seq, gf, bf, out);
    }
}

// Round 5
// 1877.072 us; speedup vs baseline: 8.4714x; 1.2674x over previous
//
#include <hip/hip_runtime.h>
#include <math.h>

#define TT 64
#define BB 2048

using f32x4   = __attribute__((ext_vector_type(4))) float;
using short8  = __attribute__((ext_vector_type(8))) short;
using short4v = __attribute__((ext_vector_type(4))) short;

__device__ __forceinline__ unsigned short f2bf(float f) {
    unsigned u = __float_as_uint(f);
    u += 0x7FFF + ((u >> 16) & 1);
    return (unsigned short)(u >> 16);
}
__device__ __forceinline__ float bf2f(unsigned short h) {
    return __uint_as_float(((unsigned)h) << 16);
}
__device__ __forceinline__ float sigmoidf_(float v) { return 1.0f / (1.0f + expf(-v)); }
__device__ __forceinline__ float tanhf_(float v)    { return 1.0f - 2.0f / (expf(2.0f * v) + 1.0f); }

// plain f32 -> bf16 row-major (Wo)
__global__ __launch_bounds__(256)
void cvt_kernel(const float* __restrict__ src, unsigned short* __restrict__ dst, int n) {
    int i = blockIdx.x * 256 + threadIdx.x;
    if (i < n) dst[i] = f2bf(src[i]);
}

// pack src[N rows][Ksrc cols] sub-block (cols kbeg..kbeg+Kpk) into MFMA fragment order:
// dst[(nf*(Kpk/32)+ks)*512 + (khi*16+llo)*8 + j] = src[nf*16+llo][kbeg + ks*32+khi*8+j]
__global__ __launch_bounds__(256)
void pack_w2(const float* __restrict__ src, unsigned short* __restrict__ dst,
             int N, int Ksrc, int kbeg, int Kpk) {
    int i = blockIdx.x * 256 + threadIdx.x;
    if (i >= N * Kpk) return;
    int n = i / Kpk, k = i - n * Kpk;
    int dstIdx = ((n >> 4) * (Kpk >> 5) + (k >> 5)) * 512 + (((k >> 3) & 3) * 16 + (n & 15)) * 8 + (k & 7);
    dst[dstIdx] = f2bf(src[(size_t)n * Ksrc + kbeg + k]);
}

// packed index inside a [16 rows][512 cols] LDS tile (fragment order)
__device__ __forceinline__ int pk_idx(int row, int col) {
    int ks = col >> 5, khi = (col >> 3) & 3, j = col & 7;
    return ((ks * 64) + khi * 16 + row) * 8 + j;
}

// LN one 512-wide row -> packed bf16 tile
__device__ __forceinline__ void ln_row_pk(const float* __restrict__ xr,
                                          const float* __restrict__ g,
                                          const float* __restrict__ b,
                                          unsigned short* __restrict__ tile,
                                          int row, int lane) {
    const int c0 = lane * 8;
    float4 v0 = *(const float4*)(xr + c0);
    float4 v1 = *(const float4*)(xr + c0 + 4);
    float s  = v0.x + v0.y + v0.z + v0.w + v1.x + v1.y + v1.z + v1.w;
    float ss = v0.x*v0.x + v0.y*v0.y + v0.z*v0.z + v0.w*v0.w
             + v1.x*v1.x + v1.y*v1.y + v1.z*v1.z + v1.w*v1.w;
#pragma unroll
    for (int m = 32; m > 0; m >>= 1) { s += __shfl_xor(s, m); ss += __shfl_xor(ss, m); }
    const float mean = s * (1.0f / 512.0f);
    const float var  = ss * (1.0f / 512.0f) - mean * mean;
    const float rs   = rsqrtf(var + 1e-5f);
    float4 g0 = *(const float4*)(g + c0);
    float4 g1 = *(const float4*)(g + c0 + 4);
    float4 b0 = *(const float4*)(b + c0);
    float4 b1 = *(const float4*)(b + c0 + 4);
    short8 o;
    o[0] = (short)f2bf((v0.x - mean) * rs * g0.x + b0.x);
    o[1] = (short)f2bf((v0.y - mean) * rs * g0.y + b0.y);
    o[2] = (short)f2bf((v0.z - mean) * rs * g0.z + b0.z);
    o[3] = (short)f2bf((v0.w - mean) * rs * g0.w + b0.w);
    o[4] = (short)f2bf((v1.x - mean) * rs * g1.x + b1.x);
    o[5] = (short)f2bf((v1.y - mean) * rs * g1.y + b1.y);
    o[6] = (short)f2bf((v1.z - mean) * rs * g1.z + b1.z);
    o[7] = (short)f2bf((v1.w - mean) * rs * g1.w + b1.w);
    *(short8*)&tile[(((lane >> 2) * 64) + (lane & 3) * 16 + row) * 8] = o;
}

// ---------------- precompute gx = LN(seq) @ [Wr_x|Wz_x|Wc_x]^T, fragment-packed bf16 ----------------
// grid 2048 blocks x 512 thr; block = 64 rows of [T*B]; Wx3 packed, cf 0..95 (r,z,c)
__global__ __launch_bounds__(512)
void gx_kernel(const float* __restrict__ seq, const float* __restrict__ gxw,
               const float* __restrict__ bxw, const unsigned short* __restrict__ Wx3,
               unsigned short* __restrict__ gx)
{
    __shared__ unsigned short xt[4 * 8192];   // 64 KB: 4 sub-tiles of [16][512] packed
    const int tid  = threadIdx.x;
    const int w    = tid >> 6;
    const int lane = tid & 63;
    const size_t m0 = (size_t)blockIdx.x * 64;
    const int t    = (int)(m0 >> 11);
    const int bloc = (int)((m0 & 2047) >> 4);

#pragma unroll
    for (int rr = 0; rr < 8; ++rr) {
        const int r = w * 8 + rr;
        ln_row_pk(seq + (m0 + r) * 512, gxw, bxw, xt + (r >> 4) * 8192, r & 15, lane);
    }
    __syncthreads();

    for (int nt = 0; nt < 3; ++nt) {
        f32x4 acc[4][4] = {};
#pragma unroll 4
        for (int ks = 0; ks < 16; ++ks) {
            short8 a[4], b[4];
#pragma unroll
            for (int mf = 0; mf < 4; ++mf)
                a[mf] = *(const short8*)&xt[mf * 8192 + (ks * 64 + lane) * 8];
#pragma unroll
            for (int nf = 0; nf < 4; ++nf)
                b[nf] = *(const short8*)(Wx3 + (size_t)(nt * 32 + w * 4 + nf) * 8192 + ks * 512 + lane * 8);
#pragma unroll
            for (int mf = 0; mf < 4; ++mf)
#pragma unroll
                for (int nf = 0; nf < 4; ++nf)
                    acc[mf][nf] = __builtin_amdgcn_mfma_f32_16x16x32_bf16(a[mf], b[nf], acc[mf][nf], 0, 0, 0);
        }
#pragma unroll
        for (int mf = 0; mf < 4; ++mf)
#pragma unroll
            for (int nf = 0; nf < 4; ++nf) {
                const size_t base = (((size_t)t * 128 + bloc + mf) * 96 + nt * 32 + w * 4 + nf) * 256 + lane * 4;
                short4v o;
                o[0] = (short)f2bf(acc[mf][nf][0]);
                o[1] = (short)f2bf(acc[mf][nf][1]);
                o[2] = (short)f2bf(acc[mf][nf][2]);
                o[3] = (short)f2bf(acc[mf][nf][3]);
                *(short4v*)&gx[base] = o;
            }
    }
}

// ---------------- block-local persistent recurrence ----------------
// 128 blocks x 512 threads; block owns 16 batch rows for ALL timesteps. No grid sync.
// HOIST=1: x-contributions come from gx (K=512 h-part weights only).
template<int SBF, int HOIST>
__global__ __launch_bounds__(512)
void recurrent_kernel(const float* __restrict__ seq, const float* __restrict__ ts,
                      const unsigned short* __restrict__ Wrz, const unsigned short* __restrict__ Wc,
                      const float* __restrict__ br, const float* __restrict__ bz,
                      const float* __restrict__ bc,
                      const float* __restrict__ gxw, const float* __restrict__ bxw,
                      const float* __restrict__ gh, const float* __restrict__ bh,
                      const float* __restrict__ gc, const float* __restrict__ bcl,
                      const unsigned short* __restrict__ gx,
                      float* __restrict__ states_f32, unsigned short* __restrict__ states_bf)
{
    __shared__ unsigned short hn_s[16 * 512];
    __shared__ unsigned short rh_s[16 * 512];
    __shared__ unsigned short xn_s[HOIST ? 64 : 16 * 512];
    __shared__ float red_s[16][8];
    __shared__ float red_q[16][8];

    const int tid  = threadIdx.x;
    const int w    = tid >> 6;
    const int lane = tid & 63;
    const int lhi  = lane >> 4;
    const int llo  = lane & 15;
    const int m0   = blockIdx.x * 16;

    for (int i = tid; i < 1024; i += 512) *(short8*)&hn_s[i * 8] = short8{};
    if (!HOIST) {
#pragma unroll
        for (int rr = 0; rr < 2; ++rr) {
            const int r = w * 2 + rr;
            ln_row_pk(seq + (size_t)(m0 + r) * 512, gxw, bxw, xn_s, r, lane);
        }
    }
    __syncthreads();

    float zreg[4][4];

    for (int t = 0; t < TT; ++t) {
        const unsigned short* gxt = HOIST ? gx + (((size_t)t * 128 + blockIdx.x) * 96) * 256 + lane * 4 : nullptr;

        // ---------- rz GEMM ----------
        {
            f32x4 aR[4] = {}, aZ[4] = {};
            if (HOIST) {
#pragma unroll
                for (int f = 0; f < 4; ++f) {
                    short4v g1 = *(const short4v*)(gxt + (size_t)(w * 4 + f) * 256);
                    short4v g2 = *(const short4v*)(gxt + (size_t)(32 + w * 4 + f) * 256);
#pragma unroll
                    for (int i = 0; i < 4; ++i) {
                        aR[f][i] = bf2f((unsigned short)g1[i]);
                        aZ[f][i] = bf2f((unsigned short)g2[i]);
                    }
                }
#pragma unroll 4
                for (int ks = 0; ks < 16; ++ks) {
                    short8 a = *(const short8*)&hn_s[(ks * 64 + lane) * 8];
                    const int off = ks * 512 + lane * 8;
#pragma unroll
                    for (int f = 0; f < 4; ++f) {
                        short8 b1 = *(const short8*)(Wrz + (size_t)(w * 4 + f) * 8192 + off);
                        aR[f] = __builtin_amdgcn_mfma_f32_16x16x32_bf16(a, b1, aR[f], 0, 0, 0);
                        short8 b2 = *(const short8*)(Wrz + (size_t)(32 + w * 4 + f) * 8192 + off);
                        aZ[f] = __builtin_amdgcn_mfma_f32_16x16x32_bf16(a, b2, aZ[f], 0, 0, 0);
                    }
                }
            } else {
                const unsigned short* wrb = Wrz + (size_t)(w * 4) * 16384;
                const unsigned short* wzb = Wrz + (size_t)(32 + w * 4) * 16384;
#pragma unroll 4
                for (int ks = 0; ks < 16; ++ks) {
                    short8 a = *(const short8*)&xn_s[(ks * 64 + lane) * 8];
                    const int off = ks * 512 + lane * 8;
#pragma unroll
                    for (int f = 0; f < 4; ++f) {
                        short8 b1 = *(const short8*)(wrb + (size_t)f * 16384 + off);
                        aR[f] = __builtin_amdgcn_mfma_f32_16x16x32_bf16(a, b1, aR[f], 0, 0, 0);
                        short8 b2 = *(const short8*)(wzb + (size_t)f * 16384 + off);
                        aZ[f] = __builtin_amdgcn_mfma_f32_16x16x32_bf16(a, b2, aZ[f], 0, 0, 0);
                    }
                }
#pragma unroll 4
                for (int ks = 16; ks < 32; ++ks) {
                    short8 a = *(const short8*)&hn_s[((ks - 16) * 64 + lane) * 8];
                    const int off = ks * 512 + lane * 8;
#pragma unroll
                    for (int f = 0; f < 4; ++f) {
                        short8 b1 = *(const short8*)(wrb + (size_t)f * 16384 + off);
                        aR[f] = __builtin_amdgcn_mfma_f32_16x16x32_bf16(a, b1, aR[f], 0, 0, 0);
                        short8 b2 = *(const short8*)(wzb + (size_t)f * 16384 + off);
                        aZ[f] = __builtin_amdgcn_mfma_f32_16x16x32_bf16(a, b2, aZ[f], 0, 0, 0);
                    }
                }
            }
#pragma unroll
            for (int f = 0; f < 4; ++f)
#pragma unroll
                for (int i = 0; i < 4; ++i) {
                    const int row = lhi * 4 + i;
                    const int col = w * 64 + f * 16 + llo;
                    const float rr = sigmoidf_(aR[f][i] + br[col]);
                    const float hv = bf2f(hn_s[pk_idx(row, col)]);
                    rh_s[pk_idx(row, col)] = f2bf(rr * hv);
                    zreg[f][i] = sigmoidf_(aZ[f][i] + bz[col]);
                }
        }
        __syncthreads();   // rh ready

        // ---------- c GEMM ----------
        f32x4 aC[4] = {};
        {
            if (HOIST) {
#pragma unroll
                for (int f = 0; f < 4; ++f) {
                    short4v g3 = *(const short4v*)(gxt + (size_t)(64 + w * 4 + f) * 256);
#pragma unroll
                    for (int i = 0; i < 4; ++i) aC[f][i] = bf2f((unsigned short)g3[i]);
                }
#pragma unroll 4
                for (int ks = 0; ks < 16; ++ks) {
                    short8 a = *(const short8*)&rh_s[(ks * 64 + lane) * 8];
                    const int off = ks * 512 + lane * 8;
#pragma unroll
                    for (int f = 0; f < 4; ++f) {
                        short8 b1 = *(const short8*)(Wc + (size_t)(w * 4 + f) * 8192 + off);
                        aC[f] = __builtin_amdgcn_mfma_f32_16x16x32_bf16(a, b1, aC[f], 0, 0, 0);
                    }
                }
            } else {
                const unsigned short* wcb = Wc + (size_t)(w * 4) * 16384;
#pragma unroll 4
                for (int ks = 0; ks < 16; ++ks) {
                    short8 a = *(const short8*)&xn_s[(ks * 64 + lane) * 8];
                    const int off = ks * 512 + lane * 8;
#pragma unroll
                    for (int f = 0; f < 4; ++f) {
                        short8 b1 = *(const short8*)(wcb + (size_t)f * 16384 + off);
                        aC[f] = __builtin_amdgcn_mfma_f32_16x16x32_bf16(a, b1, aC[f], 0, 0, 0);
                    }
                }
#pragma unroll 4
                for (int ks = 16; ks < 32; ++ks) {
                    short8 a = *(const short8*)&rh_s[((ks - 16) * 64 + lane) * 8];
                    const int off = ks * 512 + lane * 8;
#pragma unroll
                    for (int f = 0; f < 4; ++f) {
                        short8 b1 = *(const short8*)(wcb + (size_t)f * 16384 + off);
                        aC[f] = __builtin_amdgcn_mfma_f32_16x16x32_bf16(a, b1, aC[f], 0, 0, 0);
                    }
                }
            }
        }
        __syncthreads();   // all LDS reads done

        // ---------- epilogue ----------
        {
            float hnew[4][4];
#pragma unroll
            for (int f = 0; f < 4; ++f)
#pragma unroll
                for (int i = 0; i < 4; ++i) {
                    const int row = lhi * 4 + i;
                    const int col = w * 64 + f * 16 + llo;
                    const float htil = tanhf_(aC[f][i] + bc[col]);
                    const float hv = bf2f(hn_s[pk_idx(row, col)]);
                    const float z = zreg[f][i];
                    hnew[f][i] = (1.0f - z) * hv + z * htil;
                }
#pragma unroll
            for (int i = 0; i < 4; ++i) {
                float s = hnew[0][i] + hnew[1][i] + hnew[2][i] + hnew[3][i];
                float q = hnew[0][i]*hnew[0][i] + hnew[1][i]*hnew[1][i]
                        + hnew[2][i]*hnew[2][i] + hnew[3][i]*hnew[3][i];
#pragma unroll
                for (int m = 8; m >= 1; m >>= 1) { s += __shfl_xor(s, m); q += __shfl_xor(q, m); }
                if (llo == 0) { red_s[lhi * 4 + i][w] = s; red_q[lhi * 4 + i][w] = q; }
            }
            __syncthreads();
            float mu[4], rsd[4];
#pragma unroll
            for (int i = 0; i < 4; ++i) {
                float s = 0.f, q = 0.f;
#pragma unroll
                for (int w2 = 0; w2 < 8; ++w2) { s += red_s[lhi * 4 + i][w2]; q += red_q[lhi * 4 + i][w2]; }
                const float m_ = s * (1.0f / 512.0f);
                mu[i]  = m_;
                rsd[i] = rsqrtf(q * (1.0f / 512.0f) - m_ * m_ + 1e-5f);
            }
#pragma unroll
            for (int f = 0; f < 4; ++f)
#pragma unroll
                for (int i = 0; i < 4; ++i) {
                    const int row = lhi * 4 + i;
                    const int col = w * 64 + f * 16 + llo;
                    const float h = (hnew[f][i] - mu[i]) * rsd[i] * gc[col] + bcl[col];
                    const size_t off = (size_t)t * BB * 512 + (size_t)(m0 + row) * 512 + col;
                    if (SBF) states_bf[off] = f2bf(h);
                    else     states_f32[off] = h;
                    hnew[f][i] = h;
                }
            if (t + 1 < TT) {
                __syncthreads();
#pragma unroll
                for (int i = 0; i < 4; ++i) {
                    float s = hnew[0][i] + hnew[1][i] + hnew[2][i] + hnew[3][i];
                    float q = hnew[0][i]*hnew[0][i] + hnew[1][i]*hnew[1][i]
                            + hnew[2][i]*hnew[2][i] + hnew[3][i]*hnew[3][i];
#pragma unroll
                    for (int m = 8; m >= 1; m >>= 1) { s += __shfl_xor(s, m); q += __shfl_xor(q, m); }
                    if (llo == 0) { red_s[lhi * 4 + i][w] = s; red_q[lhi * 4 + i][w] = q; }
                }
                __syncthreads();
                float dec_[4];
#pragma unroll
                for (int i = 0; i < 4; ++i) {
                    float s = 0.f, q = 0.f;
#pragma unroll
                    for (int w2 = 0; w2 < 8; ++w2) { s += red_s[lhi * 4 + i][w2]; q += red_q[lhi * 4 + i][w2]; }
                    const float m_ = s * (1.0f / 512.0f);
                    mu[i]  = m_;
                    rsd[i] = rsqrtf(q * (1.0f / 512.0f) - m_ * m_ + 1e-5f);
                    const int row = m0 + lhi * 4 + i;
                    float dtv = ts[(size_t)row * TT + t + 1] - ts[(size_t)row * TT + t];
                    dtv = fminf(fmaxf(dtv, 0.0f), 10.0f);
                    dec_[i] = expf(-dtv);
                }
#pragma unroll
                for (int f = 0; f < 4; ++f)
#pragma unroll
                    for (int i = 0; i < 4; ++i) {
                        const int row = lhi * 4 + i;
                        const int col = w * 64 + f * 16 + llo;
                        const float hv = ((hnew[f][i] - mu[i]) * rsd[i] * gh[col] + bh[col]) * dec_[i];
                        hn_s[pk_idx(row, col)] = f2bf(hv);
                    }
                if (!HOIST) {
#pragma unroll
                    for (int rr = 0; rr < 2; ++rr) {
                        const int r = w * 2 + rr;
                        ln_row_pk(seq + ((size_t)(t + 1) * BB + m0 + r) * 512, gxw, bxw, xn_s, r, lane);
                    }
                }
            }
        }
        __syncthreads();
    }
}

// ---------------- final projection + residual + LN (in-place safe) ----------------
template<int BF>
__global__ __launch_bounds__(512)
void proj_kernel(const float* __restrict__ S, const unsigned short* __restrict__ Sb,
                 const unsigned short* __restrict__ Wo, const float* __restrict__ bo,
                 const float* __restrict__ seq, const float* __restrict__ gf,
                 const float* __restrict__ bff, float* __restrict__ out)
{
    const int tid  = threadIdx.x;
    const int wave = tid >> 6;
    const int lane = tid & 63;
    const int lhi  = lane >> 4;
    const int llo  = lane & 15;
    const long m0  = (long)blockIdx.x * 64;

    f32x4 acc[4][4] = {};
    for (int k0 = 0; k0 < 512; k0 += 32) {
        const int kk = k0 + lhi * 8;
        short8 a[4], b[4];
#pragma unroll
        for (int mf = 0; mf < 4; ++mf) {
            if (BF) {
                a[mf] = *(const short8*)(Sb + (size_t)(m0 + mf * 16 + llo) * 512 + kk);
            } else {
                const float* ap = S + (size_t)(m0 + mf * 16 + llo) * 512 + kk;
                float4 f0 = *(const float4*)ap;
                float4 f1 = *(const float4*)(ap + 4);
                short8 av;
                av[0] = (short)f2bf(f0.x); av[1] = (short)f2bf(f0.y);
                av[2] = (short)f2bf(f0.z); av[3] = (short)f2bf(f0.w);
                av[4] = (short)f2bf(f1.x); av[5] = (short)f2bf(f1.y);
                av[6] = (short)f2bf(f1.z); av[7] = (short)f2bf(f1.w);
                a[mf] = av;
            }
        }
#pragma unroll
        for (int nf = 0; nf < 4; ++nf)
            b[nf] = *(const short8*)(Wo + (size_t)(wave * 64 + nf * 16 + llo) * 512 + kk);
#pragma unroll
        for (int mf = 0; mf < 4; ++mf)
#pragma unroll
            for (int nf = 0; nf < 4; ++nf)
                acc[mf][nf] = __builtin_amdgcn_mfma_f32_16x16x32_bf16(a[mf], b[nf], acc[mf][nf], 0, 0, 0);
    }

    __shared__ float red_s[64][8];
    __shared__ float red_q[64][8];

#pragma unroll
    for (int mf = 0; mf < 4; ++mf)
#pragma unroll
        for (int i = 0; i < 4; ++i) {
            const long row = m0 + mf * 16 + lhi * 4 + i;
#pragma unroll
            for (int nf = 0; nf < 4; ++nf) {
                const int col = wave * 64 + nf * 16 + llo;
                acc[mf][nf][i] += bo[col] + seq[(size_t)row * 512 + col];
            }
        }
    float mu[4][4], rstd[4][4];
#pragma unroll
    for (int mf = 0; mf < 4; ++mf)
#pragma unroll
        for (int i = 0; i < 4; ++i) {
            float s = 0.f, q = 0.f;
#pragma unroll
            for (int nf = 0; nf < 4; ++nf) { const float v = acc[mf][nf][i]; s += v; q += v * v; }
#pragma unroll
            for (int m = 8; m >= 1; m >>= 1) { s += __shfl_xor(s, m); q += __shfl_xor(q, m); }
            if (llo == 0) { red_s[mf * 16 + lhi * 4 + i][wave] = s; red_q[mf * 16 + lhi * 4 + i][wave] = q; }
        }
    __syncthreads();
#pragma unroll
    for (int mf = 0; mf < 4; ++mf)
#pragma unroll
        for (int i = 0; i < 4; ++i) {
            const int rl = mf * 16 + lhi * 4 + i;
            float s = 0.f, q = 0.f;
#pragma unroll
            for (int w2 = 0; w2 < 8; ++w2) { s += red_s[rl][w2]; q += red_q[rl][w2]; }
            const float m_ = s * (1.0f / 512.0f);
            const float var = q * (1.0f / 512.0f) - m_ * m_;
            mu[mf][i] = m_;
            rstd[mf][i] = rsqrtf(var + 1e-5f);
        }
#pragma unroll
    for (int mf = 0; mf < 4; ++mf)
#pragma unroll
        for (int i = 0; i < 4; ++i) {
            const long row = m0 + mf * 16 + lhi * 4 + i;
#pragma unroll
            for (int nf = 0; nf < 4; ++nf) {
                const int col = wave * 64 + nf * 16 + llo;
                out[(size_t)row * 512 + col] = (acc[mf][nf][i] - mu[mf][i]) * rstd[mf][i] * gf[col] + bff[col];
            }
        }
}

extern "C" void kernel_launch(void* const* d_in, const int* in_sizes, int n_in,
                              void* d_out, int out_size, void* d_ws, size_t ws_size,
                              hipStream_t stream) {
    const float* seq = (const float*)d_in[0];
    const float* ts  = (const float*)d_in[1];
    const float* Wr  = (const float*)d_in[2];
    const float* br  = (const float*)d_in[3];
    const float* Wz  = (const float*)d_in[4];
    const float* bz  = (const float*)d_in[5];
    const float* Wc  = (const float*)d_in[6];
    const float* bc  = (const float*)d_in[7];
    const float* Wo  = (const float*)d_in[8];
    const float* bo  = (const float*)d_in[9];
    const float* gx  = (const float*)d_in[10];
    const float* bx  = (const float*)d_in[11];
    const float* gh  = (const float*)d_in[12];
    const float* bh  = (const float*)d_in[13];
    const float* gc  = (const float*)d_in[14];
    const float* bcl = (const float*)d_in[15];
    const float* gf  = (const float*)d_in[16];
    const float* bf  = (const float*)d_in[17];
    float* out = (float*)d_out;

    char* w0 = (char*)d_ws;
    char* w = w0;
    unsigned short* Wrz_full = (unsigned short*)w; w += (size_t)1024 * 1024 * 2;
    unsigned short* Wc_full  = (unsigned short*)w; w += (size_t)512 * 1024 * 2;
    unsigned short* Wrz_h    = (unsigned short*)w; w += (size_t)1024 * 512 * 2;
    unsigned short* Wc_h     = (unsigned short*)w; w += (size_t)512 * 512 * 2;
    unsigned short* Wx3      = (unsigned short*)w; w += (size_t)1536 * 512 * 2;
    unsigned short* Wo_b     = (unsigned short*)w; w += (size_t)512 * 512 * 2;

    const size_t GXB = (size_t)TT * 128 * 96 * 256 * 2;      // 402,653,184
    const size_t SBB = (size_t)TT * BB * 512 * 2;            // 134,217,728

    const bool hoist = ws_size >= (size_t)(w - w0) + GXB;
    unsigned short* gxbuf = (unsigned short*)w;
    if (hoist) w += GXB;
    const bool sbf = ws_size >= (size_t)(w - w0) + SBB;
    unsigned short* states_bf = (unsigned short*)w;

    if (hoist) {
        pack_w2<<<1024, 256, 0, stream>>>(Wr, Wrz_h, 512, 1024, 512, 512);
        pack_w2<<<1024, 256, 0, stream>>>(Wz, Wrz_h + (size_t)512 * 512, 512, 1024, 512, 512);
        pack_w2<<<1024, 256, 0, stream>>>(Wc, Wc_h, 512, 1024, 512, 512);
        pack_w2<<<1024, 256, 0, stream>>>(Wr, Wx3, 512, 1024, 0, 512);
        pack_w2<<<1024, 256, 0, stream>>>(Wz, Wx3 + (size_t)512 * 512, 512, 1024, 0, 512);
        pack_w2<<<1024, 256, 0, stream>>>(Wc, Wx3 + (size_t)2 * 512 * 512, 512, 1024, 0, 512);
    } else {
        pack_w2<<<2048, 256, 0, stream>>>(Wr, Wrz_full, 512, 1024, 0, 1024);
        pack_w2<<<2048, 256, 0, stream>>>(Wz, Wrz_full + (size_t)512 * 1024, 512, 1024, 0, 1024);
        pack_w2<<<2048, 256, 0, stream>>>(Wc, Wc_full, 512, 1024, 0, 1024);
    }
    cvt_kernel<<<(512 * 512 + 255) / 256, 256, 0, stream>>>(Wo, Wo_b, 512 * 512);

    if (hoist)
        gx_kernel<<<2048, 512, 0, stream>>>(seq, gx, bx, Wx3, gxbuf);

    const unsigned short* Wa = hoist ? Wrz_h : Wrz_full;
    const unsigned short* Wb = hoist ? Wc_h  : Wc_full;
    if (hoist) {
        if (sbf) recurrent_kernel<1,1><<<128, 512, 0, stream>>>(seq, ts, Wa, Wb, br, bz, bc, gx, bx, gh, bh, gc, bcl, gxbuf, out, states_bf);
        else     recurrent_kernel<0,1><<<128, 512, 0, stream>>>(seq, ts, Wa, Wb, br, bz, bc, gx, bx, gh, bh, gc, bcl, gxbuf, out, states_bf);
    } else {
        if (sbf) recurrent_kernel<1,0><<<128, 512, 0, stream>>>(seq, ts, Wa, Wb, br, bz, bc, gx, bx, gh, bh, gc, bcl, gxbuf, out, states_bf);
        else     recurrent_kernel<0,0><<<128, 512, 0, stream>>>(seq, ts, Wa, Wb, br, bz, bc, gx, bx, gh, bh, gc, bcl, gxbuf, out, states_bf);
    }

    if (sbf)
        proj_kernel<1><<<2048, 512, 0, stream>>>(out, states_bf, Wo_b, bo, seq, gf, bf, out);
    else
        proj_kernel<0><<<2048, 512, 0, stream>>>(out, nullptr, Wo_b, bo, seq, gf, bf, out);
}